// Round 2
// baseline (306.776 us; speedup 1.0000x reference)
//
#include <hip/hip_runtime.h>

#define D 64
#define K 512
#define NVEC 131072   // 8192 * 16
#define BLOCK 256

// Kernel A: w2half[k] = 0.5 * |w_k|^2 ; also zero the loss slot.
__global__ __launch_bounds__(64) void vq_prep(const float* __restrict__ w,
                                              float* __restrict__ w2half,
                                              float* __restrict__ loss_slot) {
    int k = blockIdx.x * 64 + threadIdx.x;
    if (blockIdx.x == 0 && threadIdx.x == 0) loss_slot[0] = 0.0f;
    if (k < K) {
        const float4* wv = (const float4*)(w + k * D);
        float s0 = 0.f, s1 = 0.f, s2 = 0.f, s3 = 0.f;
#pragma unroll
        for (int i = 0; i < D / 4; ++i) {
            float4 t = wv[i];
            s0 = fmaf(t.x, t.x, s0);
            s1 = fmaf(t.y, t.y, s1);
            s2 = fmaf(t.z, t.z, s2);
            s3 = fmaf(t.w, t.w, s3);
        }
        w2half[k] = 0.5f * ((s0 + s1) + (s2 + s3));
    }
}

// Kernel B: one thread per z-vector. score(k) = 0.5|w_k|^2 - z.w_k  (argmin
// identical to squared distance, monotone transform of the reference's d2).
// Codebook accessed at wave-uniform addresses -> scalar loads; z in VGPRs;
// 4 independent FMA chains hide the 4-cycle dependent-FMA latency.
__global__ __launch_bounds__(BLOCK) void vq_main(const float* __restrict__ z_all,
                                                 const float* __restrict__ w,
                                                 const float* __restrict__ w2half,
                                                 float* __restrict__ out,
                                                 float* __restrict__ loss_slot) {
    const int v = blockIdx.x * BLOCK + threadIdx.x;

    // Load z (negated so the inner loop is a pure fma: acc += (-z)*w).
    const float4* zv = (const float4*)(z_all + (size_t)v * D);
    float zn[D];
#pragma unroll
    for (int i = 0; i < D / 4; ++i) {
        float4 t = zv[i];
        zn[4 * i + 0] = -t.x;
        zn[4 * i + 1] = -t.y;
        zn[4 * i + 2] = -t.z;
        zn[4 * i + 3] = -t.w;
    }

    float best = 3.402823466e+38f;
    int bidx = 0;
    for (int k = 0; k < K; ++k) {
        const float* __restrict__ wk = w + k * D;  // wave-uniform address
        float a0 = w2half[k], a1 = 0.f, a2 = 0.f, a3 = 0.f;
#pragma unroll
        for (int dd = 0; dd < D; dd += 4) {
            a0 = fmaf(zn[dd + 0], wk[dd + 0], a0);
            a1 = fmaf(zn[dd + 1], wk[dd + 1], a1);
            a2 = fmaf(zn[dd + 2], wk[dd + 2], a2);
            a3 = fmaf(zn[dd + 3], wk[dd + 3], a3);
        }
        float s = (a0 + a1) + (a2 + a3);
        bool lt = s < best;            // strict < keeps first index (jnp.argmin)
        best = lt ? s : best;
        bidx = lt ? k : bidx;
    }

    // Output: out = z + (q - z)  (mimic reference STE rounding exactly); loss
    // accumulated elementwise as 1.25*(q - z)^2 (codebook + 0.25*commitment,
    // identical elementwise since both are (q-z)^2 with stop-gradients).
    const float4* qv = (const float4*)(w + bidx * D);
    float4* ov = (float4*)(out + (size_t)v * D);
    float lsum = 0.f;
#pragma unroll
    for (int i = 0; i < D / 4; ++i) {
        float4 q = qv[i];
        float z0 = -zn[4 * i + 0], z1 = -zn[4 * i + 1];
        float z2 = -zn[4 * i + 2], z3 = -zn[4 * i + 3];
        float t0 = q.x - z0, t1 = q.y - z1, t2 = q.z - z2, t3 = q.w - z3;
        float4 o;
        o.x = z0 + t0;
        o.y = z1 + t1;
        o.z = z2 + t2;
        o.w = z3 + t3;
        ov[i] = o;
        lsum = fmaf(t0, t0, lsum);
        lsum = fmaf(t1, t1, lsum);
        lsum = fmaf(t2, t2, lsum);
        lsum = fmaf(t3, t3, lsum);
    }

    // Block reduction of the loss partial sums.
#pragma unroll
    for (int off = 32; off > 0; off >>= 1) lsum += __shfl_down(lsum, off, 64);
    __shared__ float red[BLOCK / 64];
    const int lane = threadIdx.x & 63;
    const int wid = threadIdx.x >> 6;
    if (lane == 0) red[wid] = lsum;
    __syncthreads();
    if (threadIdx.x == 0) {
        float s = 0.f;
#pragma unroll
        for (int i = 0; i < BLOCK / 64; ++i) s += red[i];
        // vq_loss = 1.25 * sum / (8192*16*64); 1.25/2^23 is exact in fp32.
        atomicAdd(loss_slot, s * (1.25f / 8388608.0f));
    }
}

extern "C" void kernel_launch(void* const* d_in, const int* in_sizes, int n_in,
                              void* d_out, int out_size, void* d_ws, size_t ws_size,
                              hipStream_t stream) {
    const float* latents = (const float*)d_in[0];   // [8192, 1024] f32
    const float* weight  = (const float*)d_in[1];   // [512, 64] f32
    float* out = (float*)d_out;                     // 8388608 outputs + 1 loss
    float* loss_slot = out + (size_t)NVEC * D;
    float* w2half = (float*)d_ws;                   // 512 floats of scratch

    vq_prep<<<8, 64, 0, stream>>>(weight, w2half, loss_slot);
    vq_main<<<NVEC / BLOCK, BLOCK, 0, stream>>>(latents, weight, w2half, out, loss_slot);
}